// Round 1
// baseline (72.717 us; speedup 1.0000x reference)
//
#include <hip/hip_runtime.h>
#include <math.h>

// KDE log-density: out[i] = log(1e-8 + (1/N) * sum_j exp(t1 - 50*||xe_i - xb_j||^2))
// N = 16384, D = 16, fp32 in/out.
//
// Round 6: grouped-screen restructure of the round-5 MFMA core.
//  - Timed region includes the harness's 256 MiB workspace re-poison
//    (fillBufferAligned, ~41 us @ 6.5 TB/s) — fixed tax. Attack kde_main.
//  - Round-5 kde_main (~25 us est.) was ~5x issue-bound theory (~5 us):
//    launch_bounds(256,8) forces a 64-VGPR budget while unroll-4 wants
//    4x16 accumulator regs -> spill/serialize; plus a branch per tile and
//    1-tile-deep prefetch vs ~200cy L2 latency.
//  - Fix: launch_bounds(256,4) (128 VGPRs), explicit 4-tile groups:
//    4 MFMAs + 4 max3-trees, ballots OR-ed into ONE uniform branch per
//    group; prefetch the next whole group; rare path RE-COMPUTES d from
//    the still-live B fragment so no accumulator survives the branch.
//    pe prologue loads vectorized to 4x float4.
//  - Gating and the exp/atomicAdd/atomicMin hit path are bit-identical to
//    round 5 (each tile still individually __any-gated).

#define KDE_N 16384
#define KDE_D 16
#define MT 32                  // rows per wave m-tile
#define MWAVES 4               // waves per block
#define MB (MT * MWAVES)       // 128 eval rows per block
#define JSPLIT 16
#define JTILES (KDE_N / 32 / JSPLIT)   // 32 j-tiles per wave
#define GROUP 4
#define NG (JTILES / GROUP)            // 8 groups per wave
#define THR (-135.0f)          // log2-domain underflow screen

typedef __attribute__((ext_vector_type(8)))  short   short8;
typedef __attribute__((ext_vector_type(16))) float   float16_t;

__device__ __forceinline__ unsigned short f32_to_bf16_rne(float f) {
    unsigned int u = __float_as_uint(f);
    unsigned int r = (u + 0x7FFFu + ((u >> 16) & 1u)) >> 16;
    return (unsigned short)r;
}

// ---- prologue: pe / (THR - pb), scaled bf16 casts, zero S, default out ----
__global__ void kde_pre(const float* __restrict__ xe, const float* __restrict__ xb,
                        float* __restrict__ S, float* __restrict__ pe,
                        float* __restrict__ pbthr, unsigned short* __restrict__ xe16,
                        unsigned short* __restrict__ xb16, float* __restrict__ out)
{
    const int t = blockIdx.x * blockDim.x + threadIdx.x;   // 0..32767
    const int row = t & (KDE_N - 1);
    const bool isB = t >= KDE_N;
    const float* src = (isB ? xb : xe) + (size_t)row * KDE_D;
    const float4* s4 = (const float4*)src;
    const float SQSC = 12.011224664550577f;   // sqrt(100*log2e)
    float q = 0.f;
    unsigned int w[8];
    #pragma unroll
    for (int k = 0; k < 4; ++k) {
        float4 v = s4[k];
        q += v.x*v.x + v.y*v.y + v.z*v.z + v.w*v.w;
        w[2*k+0] = (unsigned int)f32_to_bf16_rne(v.x * SQSC)
                 | ((unsigned int)f32_to_bf16_rne(v.y * SQSC) << 16);
        w[2*k+1] = (unsigned int)f32_to_bf16_rne(v.z * SQSC)
                 | ((unsigned int)f32_to_bf16_rne(v.w * SQSC) << 16);
    }
    unsigned short* dst = (isB ? xb16 : xe16) + (size_t)row * KDE_D;
    uint4* d4 = (uint4*)dst;
    d4[0] = make_uint4(w[0], w[1], w[2], w[3]);
    d4[1] = make_uint4(w[4], w[5], w[6], w[7]);
    const float T1L2E  = -17.8920067984f;       // log2e * t1
    const float C72    = 72.134752044447963f;   // 50 * log2e
    const float LOG1EM8 = -18.420680743952367f; // log(1e-8)
    if (!isB) { pe[row] = T1L2E - C72 * q; S[row] = 0.f; out[row] = LOG1EM8; }
    else      { pbthr[row] = THR + C72 * q; }   // THR - pb,  pb = -C72*b2
}

// ---- main: 4-tile grouped MFMA + max-screen; one uniform branch / group ----
__global__ __launch_bounds__(256, 4) void kde_main(
    const unsigned short* __restrict__ xe16, const unsigned short* __restrict__ xb16,
    const float* __restrict__ pe, const float* __restrict__ pbthr,
    float* __restrict__ S, float* __restrict__ out)
{
    const int lane = threadIdx.x & 63;
    const int wave = threadIdx.x >> 6;
    const int m0   = blockIdx.x * MB + wave * MT;
    const int jt0  = blockIdx.y * JTILES;

    const int col  = lane & 31;   // A row / B col / C col
    const int half = lane >> 5;   // k-half for A/B frags; row-group for C

    // A fragment, loaded once (K=16 == D)
    const short8 af = *(const short8*)(xe16 + (size_t)(m0 + col) * KDE_D + half * 8);

    // C operand = pe for the 16 C rows this lane owns:
    // row(r) = (r&3) + 8*(r>>2) + 4*half  -> 4 contiguous quads at +0/+8/+16/+24
    const float4* pq = (const float4*)(pe + m0 + 4 * half);
    const float4 q0 = pq[0], q1 = pq[2], q2 = pq[4], q3 = pq[6];
    float16_t perv;
    perv[0]=q0.x;  perv[1]=q0.y;  perv[2]=q0.z;  perv[3]=q0.w;
    perv[4]=q1.x;  perv[5]=q1.y;  perv[6]=q1.z;  perv[7]=q1.w;
    perv[8]=q2.x;  perv[9]=q2.y;  perv[10]=q2.z; perv[11]=q2.w;
    perv[12]=q3.x; perv[13]=q3.y; perv[14]=q3.z; perv[15]=q3.w;

    const float INVN = 1.0f / (float)KDE_N;

    // max over this lane's 16 accumulator values, max3-friendly shape
    auto tree = [](const float16_t& d) -> float {
        float m1 = fmaxf(fmaxf(d[0],  d[1]),  d[2]);
        float m2 = fmaxf(fmaxf(d[3],  d[4]),  d[5]);
        float m3 = fmaxf(fmaxf(d[6],  d[7]),  d[8]);
        float m4 = fmaxf(fmaxf(d[9],  d[10]), d[11]);
        float m5 = fmaxf(fmaxf(d[12], d[13]), d[14]);
        float x  = fmaxf(fmaxf(m1, m2), m3);
        float y  = fmaxf(fmaxf(m4, m5), d[15]);
        return fmaxf(x, y);
    };

    // rare hit path: recompute d (B frag still live), update S and out
    auto rare = [&](const short8& bfrag, float thrv) {
        float16_t d = __builtin_amdgcn_mfma_f32_32x32x16_bf16(af, bfrag, perv, 0, 0, 0);
        const float pbv = THR - thrv;
        #pragma unroll
        for (int r = 0; r < 16; ++r) {
            float e = exp2f(d[r] + pbv);
            if (e != 0.f) {
                const int row = m0 + (r & 3) + 8 * (r >> 2) + 4 * half;
                float old  = atomicAdd(&S[row], e);
                float cand = logf(1e-8f + (old + e) * INVN);
                // all cands negative: float-max == uint-min on raw bits
                atomicMin((unsigned int*)&out[row], __float_as_uint(cand));
            }
        }
    };

    const unsigned short* bp = xb16 + (size_t)(jt0 * 32 + col) * KDE_D + half * 8;
    const float*          tp = pbthr + (jt0 * 32 + col);

    short8 b0 = *(const short8*)(bp);
    short8 b1 = *(const short8*)(bp + 32 * KDE_D);
    short8 b2 = *(const short8*)(bp + 64 * KDE_D);
    short8 b3 = *(const short8*)(bp + 96 * KDE_D);
    float  t0 = tp[0], t1 = tp[32], t2 = tp[64], t3 = tp[96];

    for (int g = 0; g < NG - 1; ++g) {
        bp += GROUP * 32 * KDE_D;
        tp += GROUP * 32;
        const short8 n0 = *(const short8*)(bp);
        const short8 n1 = *(const short8*)(bp + 32 * KDE_D);
        const short8 n2 = *(const short8*)(bp + 64 * KDE_D);
        const short8 n3 = *(const short8*)(bp + 96 * KDE_D);
        const float  u0 = tp[0], u1 = tp[32], u2 = tp[64], u3 = tp[96];

        const float16_t d0 = __builtin_amdgcn_mfma_f32_32x32x16_bf16(af, b0, perv, 0, 0, 0);
        const float mx0 = tree(d0);
        const float16_t d1 = __builtin_amdgcn_mfma_f32_32x32x16_bf16(af, b1, perv, 0, 0, 0);
        const float mx1 = tree(d1);
        const float16_t d2 = __builtin_amdgcn_mfma_f32_32x32x16_bf16(af, b2, perv, 0, 0, 0);
        const float mx2 = tree(d2);
        const float16_t d3 = __builtin_amdgcn_mfma_f32_32x32x16_bf16(af, b3, perv, 0, 0, 0);
        const float mx3 = tree(d3);

        const unsigned long long h = __ballot(mx0 > t0) | __ballot(mx1 > t1)
                                   | __ballot(mx2 > t2) | __ballot(mx3 > t3);
        if (h) {   // uniform, astronomically rare
            if (__any(mx0 > t0)) rare(b0, t0);
            if (__any(mx1 > t1)) rare(b1, t1);
            if (__any(mx2 > t2)) rare(b2, t2);
            if (__any(mx3 > t3)) rare(b3, t3);
        }
        b0 = n0; b1 = n1; b2 = n2; b3 = n3;
        t0 = u0; t1 = u1; t2 = u2; t3 = u3;
    }

    {   // peeled last group (no prefetch)
        const float16_t d0 = __builtin_amdgcn_mfma_f32_32x32x16_bf16(af, b0, perv, 0, 0, 0);
        const float mx0 = tree(d0);
        const float16_t d1 = __builtin_amdgcn_mfma_f32_32x32x16_bf16(af, b1, perv, 0, 0, 0);
        const float mx1 = tree(d1);
        const float16_t d2 = __builtin_amdgcn_mfma_f32_32x32x16_bf16(af, b2, perv, 0, 0, 0);
        const float mx2 = tree(d2);
        const float16_t d3 = __builtin_amdgcn_mfma_f32_32x32x16_bf16(af, b3, perv, 0, 0, 0);
        const float mx3 = tree(d3);

        const unsigned long long h = __ballot(mx0 > t0) | __ballot(mx1 > t1)
                                   | __ballot(mx2 > t2) | __ballot(mx3 > t3);
        if (h) {
            if (__any(mx0 > t0)) rare(b0, t0);
            if (__any(mx1 > t1)) rare(b1, t1);
            if (__any(mx2 > t2)) rare(b2, t2);
            if (__any(mx3 > t3)) rare(b3, t3);
        }
    }
}

extern "C" void kernel_launch(void* const* d_in, const int* in_sizes, int n_in,
                              void* d_out, int out_size, void* d_ws, size_t ws_size,
                              hipStream_t stream)
{
    const float* xe = (const float*)d_in[0];  // x_eval [16384,16] fp32
    const float* xb = (const float*)d_in[1];  // x_base [16384,16] fp32
    float* out = (float*)d_out;

    // ws layout: S[16384] | pe[16384] | pbthr[16384] | xe16 | xb16
    float* S     = (float*)d_ws;
    float* pe    = S + KDE_N;
    float* pbthr = pe + KDE_N;
    unsigned short* xe16 = (unsigned short*)(pbthr + KDE_N);
    unsigned short* xb16 = xe16 + (size_t)KDE_N * KDE_D;

    kde_pre<<<(2 * KDE_N) / 256, 256, 0, stream>>>(xe, xb, S, pe, pbthr, xe16, xb16, out);
    dim3 grid(KDE_N / MB, JSPLIT);   // (128, 16) = 2048 blocks
    kde_main<<<grid, MWAVES * 64, 0, stream>>>(xe16, xb16, pe, pbthr, S, out);
}

// Round 2
// 72.607 us; speedup vs baseline: 1.0015x; 1.0015x over previous
//
#include <hip/hip_runtime.h>
#include <math.h>

// KDE log-density: out[i] = log(1e-8 + (1/N) * sum_j exp(t1 - 50*||xe_i - xb_j||^2))
// N = 16384, D = 16, fp32 in/out.
//
// Round 7: round-5 structure (launch_bounds(256,8), prefetch-1, unroll 4,
// per-tile __any screen) with the FAT RARE PATH EVICTED from the loop.
//  - Round-6 post-mortem: grouping + (256,4) made it worse (69.1->72.7).
//    Occupancy halved (grid lost full residency: 2048 blocks = 8/CU at
//    (256,8)); the doubled VGPR budget didn't pay. Revised theory: the
//    exp2f/logf/atomic code inside the loop inflates live state past the
//    64-VGPR cap -> in-loop spills (round 5) or occupancy loss (round 6).
//  - Fix: in-loop hit handling is ONE scalar op: hitmask |= 1<<t under a
//    wave-uniform __any. After the loop, if (hitmask) — never taken in
//    practice — replay each hit tile: reload B frag, redo the SAME MFMA
//    (bit-identical d), then the exact round-5 exp/atomicAdd/atomicMin
//    sequence. Loop live state ~60 VGPRs -> fits 64, no spill, 8 waves/SIMD.
//  - Screen math, gating, and hit-path numerics are bit-identical to round 5.

#define KDE_N 16384
#define KDE_D 16
#define MT 32                  // rows per wave m-tile
#define MWAVES 4               // waves per block
#define MB (MT * MWAVES)       // 128 eval rows per block
#define JSPLIT 16
#define JTILES (KDE_N / 32 / JSPLIT)   // 32 j-tiles per wave (fits 32-bit hitmask)
#define THR (-135.0f)          // log2-domain underflow screen

typedef __attribute__((ext_vector_type(8)))  short   short8;
typedef __attribute__((ext_vector_type(16))) float   float16_t;

__device__ __forceinline__ unsigned short f32_to_bf16_rne(float f) {
    unsigned int u = __float_as_uint(f);
    unsigned int r = (u + 0x7FFFu + ((u >> 16) & 1u)) >> 16;
    return (unsigned short)r;
}

// ---- prologue: pe / (THR - pb), scaled bf16 casts, zero S, default out ----
__global__ void kde_pre(const float* __restrict__ xe, const float* __restrict__ xb,
                        float* __restrict__ S, float* __restrict__ pe,
                        float* __restrict__ pbthr, unsigned short* __restrict__ xe16,
                        unsigned short* __restrict__ xb16, float* __restrict__ out)
{
    const int t = blockIdx.x * blockDim.x + threadIdx.x;   // 0..32767
    const int row = t & (KDE_N - 1);
    const bool isB = t >= KDE_N;
    const float* src = (isB ? xb : xe) + (size_t)row * KDE_D;
    const float4* s4 = (const float4*)src;
    const float SQSC = 12.011224664550577f;   // sqrt(100*log2e)
    float q = 0.f;
    unsigned int w[8];
    #pragma unroll
    for (int k = 0; k < 4; ++k) {
        float4 v = s4[k];
        q += v.x*v.x + v.y*v.y + v.z*v.z + v.w*v.w;
        w[2*k+0] = (unsigned int)f32_to_bf16_rne(v.x * SQSC)
                 | ((unsigned int)f32_to_bf16_rne(v.y * SQSC) << 16);
        w[2*k+1] = (unsigned int)f32_to_bf16_rne(v.z * SQSC)
                 | ((unsigned int)f32_to_bf16_rne(v.w * SQSC) << 16);
    }
    unsigned short* dst = (isB ? xb16 : xe16) + (size_t)row * KDE_D;
    uint4* d4 = (uint4*)dst;
    d4[0] = make_uint4(w[0], w[1], w[2], w[3]);
    d4[1] = make_uint4(w[4], w[5], w[6], w[7]);
    const float T1L2E  = -17.8920067984f;       // log2e * t1
    const float C72    = 72.134752044447963f;   // 50 * log2e
    const float LOG1EM8 = -18.420680743952367f; // log(1e-8)
    if (!isB) { pe[row] = T1L2E - C72 * q; S[row] = 0.f; out[row] = LOG1EM8; }
    else      { pbthr[row] = THR + C72 * q; }   // THR - pb,  pb = -C72*b2
}

// ---- main: lean MFMA + max-screen loop; hits recorded in a scalar mask ----
__global__ __launch_bounds__(256, 8) void kde_main(
    const unsigned short* __restrict__ xe16, const unsigned short* __restrict__ xb16,
    const float* __restrict__ pe, const float* __restrict__ pbthr,
    float* __restrict__ S, float* __restrict__ out)
{
    const int lane = threadIdx.x & 63;
    const int wave = threadIdx.x >> 6;
    const int m0   = blockIdx.x * MB + wave * MT;
    const int jt0  = blockIdx.y * JTILES;

    const int col  = lane & 31;   // A row / B col / C col
    const int half = lane >> 5;   // k-half for A/B frags; row-group for C

    // A fragment, loaded once (K=16 == D)
    const short8 af = *(const short8*)(xe16 + (size_t)(m0 + col) * KDE_D + half * 8);

    // C operand = pe for the 16 C rows this lane owns:
    // row(r) = (r&3) + 8*(r>>2) + 4*half  -> 4 contiguous quads at +0/+8/+16/+24
    const float4* pq = (const float4*)(pe + m0 + 4 * half);
    const float4 q0 = pq[0], q1 = pq[2], q2 = pq[4], q3 = pq[6];
    float16_t perv;
    perv[0]=q0.x;  perv[1]=q0.y;  perv[2]=q0.z;  perv[3]=q0.w;
    perv[4]=q1.x;  perv[5]=q1.y;  perv[6]=q1.z;  perv[7]=q1.w;
    perv[8]=q2.x;  perv[9]=q2.y;  perv[10]=q2.z; perv[11]=q2.w;
    perv[12]=q3.x; perv[13]=q3.y; perv[14]=q3.z; perv[15]=q3.w;

    // max over this lane's 16 accumulator values, max3-friendly shape
    auto tree = [](const float16_t& d) -> float {
        float m1 = fmaxf(fmaxf(d[0],  d[1]),  d[2]);
        float m2 = fmaxf(fmaxf(d[3],  d[4]),  d[5]);
        float m3 = fmaxf(fmaxf(d[6],  d[7]),  d[8]);
        float m4 = fmaxf(fmaxf(d[9],  d[10]), d[11]);
        float m5 = fmaxf(fmaxf(d[12], d[13]), d[14]);
        float x  = fmaxf(fmaxf(m1, m2), m3);
        float y  = fmaxf(fmaxf(m4, m5), d[15]);
        return fmaxf(x, y);
    };

    const unsigned short* bp = xb16 + (size_t)(jt0 * 32 + col) * KDE_D + half * 8;
    const float*          tp = pbthr + (jt0 * 32 + col);
    short8 bf   = *(const short8*)bp;
    float  thrv = *tp;

    unsigned int hitmask = 0;   // wave-uniform -> stays scalar

    #pragma unroll 4
    for (int t = 0; t < JTILES - 1; ++t) {
        bp += 32 * KDE_D;  tp += 32;
        const short8 bf_n  = *(const short8*)bp;
        const float  thr_n = *tp;
        const float16_t d = __builtin_amdgcn_mfma_f32_32x32x16_bf16(af, bf, perv, 0, 0, 0);
        const float mx = tree(d);
        if (__any(mx > thrv)) hitmask |= (1u << t);
        bf = bf_n; thrv = thr_n;
    }
    {   // peeled last tile (no prefetch)
        const float16_t d = __builtin_amdgcn_mfma_f32_32x32x16_bf16(af, bf, perv, 0, 0, 0);
        const float mx = tree(d);
        if (__any(mx > thrv)) hitmask |= (1u << (JTILES - 1));
    }

    // ---- cold replay path: astronomically rare, bit-identical numerics ----
    if (hitmask) {
        const float INVN = 1.0f / (float)KDE_N;
        const unsigned short* bbase = xb16 + (size_t)(jt0 * 32 + col) * KDE_D + half * 8;
        while (hitmask) {
            const int t = __builtin_ctz(hitmask);
            hitmask &= hitmask - 1;
            const short8 bh   = *(const short8*)(bbase + (size_t)t * 32 * KDE_D);
            const float  thrh = pbthr[jt0 * 32 + col + t * 32];
            const float16_t d = __builtin_amdgcn_mfma_f32_32x32x16_bf16(af, bh, perv, 0, 0, 0);
            const float pbv = THR - thrh;
            #pragma unroll
            for (int r = 0; r < 16; ++r) {
                float e = exp2f(d[r] + pbv);
                if (e != 0.f) {
                    const int row = m0 + (r & 3) + 8 * (r >> 2) + 4 * half;
                    float old  = atomicAdd(&S[row], e);
                    float cand = logf(1e-8f + (old + e) * INVN);
                    // all cands negative: float-max == uint-min on raw bits
                    atomicMin((unsigned int*)&out[row], __float_as_uint(cand));
                }
            }
        }
    }
}

extern "C" void kernel_launch(void* const* d_in, const int* in_sizes, int n_in,
                              void* d_out, int out_size, void* d_ws, size_t ws_size,
                              hipStream_t stream)
{
    const float* xe = (const float*)d_in[0];  // x_eval [16384,16] fp32
    const float* xb = (const float*)d_in[1];  // x_base [16384,16] fp32
    float* out = (float*)d_out;

    // ws layout: S[16384] | pe[16384] | pbthr[16384] | xe16 | xb16
    float* S     = (float*)d_ws;
    float* pe    = S + KDE_N;
    float* pbthr = pe + KDE_N;
    unsigned short* xe16 = (unsigned short*)(pbthr + KDE_N);
    unsigned short* xb16 = xe16 + (size_t)KDE_N * KDE_D;

    kde_pre<<<(2 * KDE_N) / 256, 256, 0, stream>>>(xe, xb, S, pe, pbthr, xe16, xb16, out);
    dim3 grid(KDE_N / MB, JSPLIT);   // (128, 16) = 2048 blocks
    kde_main<<<grid, MWAVES * 64, 0, stream>>>(xe16, xb16, pe, pbthr, S, out);
}

// Round 3
// 68.364 us; speedup vs baseline: 1.0637x; 1.0621x over previous
//
#include <hip/hip_runtime.h>
#include <math.h>

// KDE log-density: out[i] = log(1e-8 + (1/N) * sum_j exp(t1 - 50*||xe_i - xb_j||^2))
// N = 16384, D = 16, fp32 in/out.
//
// Round 8: EXACT round-5 kernel (69.1 us, best known) + ONE change: grid
// dimension swap for L1 locality.
//  - Rounds 6/7 post-mortem: leaner in-loop bodies (grouped screen; hitmask
//    eviction) both landed at ~72.6 us vs round-5's 69.1 -> in-loop
//    instruction count is NOT the bottleneck. Reverted wholesale.
//  - Theory: with grid(x=128 m-blocks, y=16 j-slices), co-resident blocks on
//    a CU are spaced 256 apart in dispatch id = x + 128*y -> same x,
//    DIFFERENT y: 8 blocks/CU want 8 different 32 KB B-slices = 256 KB vs
//    32 KB L1 -> every B load misses L1, queues on L2, stalls at prefetch
//    depth 1.
//  - Fix: grid(16, 128), id = jx + 16*my; id+256k keeps jx -> all 8
//    co-resident blocks share ONE 32 KB B-slice = exactly L1-sized.
//    jt0 <- blockIdx.x, m0 <- blockIdx.y. Nothing else changed.

#define KDE_N 16384
#define KDE_D 16
#define MT 32                  // rows per wave m-tile
#define MWAVES 4               // waves per block
#define MB (MT * MWAVES)       // 128 eval rows per block
#define JSPLIT 16
#define JTILES (KDE_N / 32 / JSPLIT)   // 32 j-tiles per wave
#define THR (-135.0f)          // log2-domain underflow screen

typedef __attribute__((ext_vector_type(8)))  short   short8;
typedef __attribute__((ext_vector_type(16))) float   float16_t;

__device__ __forceinline__ unsigned short f32_to_bf16_rne(float f) {
    unsigned int u = __float_as_uint(f);
    unsigned int r = (u + 0x7FFFu + ((u >> 16) & 1u)) >> 16;
    return (unsigned short)r;
}

// ---- prologue: pe / (THR - pb), scaled bf16 casts, zero S, default out ----
__global__ void kde_pre(const float* __restrict__ xe, const float* __restrict__ xb,
                        float* __restrict__ S, float* __restrict__ pe,
                        float* __restrict__ pbthr, unsigned short* __restrict__ xe16,
                        unsigned short* __restrict__ xb16, float* __restrict__ out)
{
    const int t = blockIdx.x * blockDim.x + threadIdx.x;   // 0..32767
    const int row = t & (KDE_N - 1);
    const bool isB = t >= KDE_N;
    const float* src = (isB ? xb : xe) + (size_t)row * KDE_D;
    const float4* s4 = (const float4*)src;
    const float SQSC = 12.011224664550577f;   // sqrt(100*log2e)
    float q = 0.f;
    unsigned int w[8];
    #pragma unroll
    for (int k = 0; k < 4; ++k) {
        float4 v = s4[k];
        q += v.x*v.x + v.y*v.y + v.z*v.z + v.w*v.w;
        w[2*k+0] = (unsigned int)f32_to_bf16_rne(v.x * SQSC)
                 | ((unsigned int)f32_to_bf16_rne(v.y * SQSC) << 16);
        w[2*k+1] = (unsigned int)f32_to_bf16_rne(v.z * SQSC)
                 | ((unsigned int)f32_to_bf16_rne(v.w * SQSC) << 16);
    }
    unsigned short* dst = (isB ? xb16 : xe16) + (size_t)row * KDE_D;
    uint4* d4 = (uint4*)dst;
    d4[0] = make_uint4(w[0], w[1], w[2], w[3]);
    d4[1] = make_uint4(w[4], w[5], w[6], w[7]);
    const float T1L2E  = -17.8920067984f;       // log2e * t1
    const float C72    = 72.134752044447963f;   // 50 * log2e
    const float LOG1EM8 = -18.420680743952367f; // log(1e-8)
    if (!isB) { pe[row] = T1L2E - C72 * q; S[row] = 0.f; out[row] = LOG1EM8; }
    else      { pbthr[row] = THR + C72 * q; }   // THR - pb,  pb = -C72*b2
}

// ---- main: MFMA + max-screen; rare exp path updates S and out directly ----
__global__ __launch_bounds__(256, 8) void kde_main(
    const unsigned short* __restrict__ xe16, const unsigned short* __restrict__ xb16,
    const float* __restrict__ pe, const float* __restrict__ pbthr,
    float* __restrict__ S, float* __restrict__ out)
{
    const int lane = threadIdx.x & 63;
    const int wave = threadIdx.x >> 6;
    const int m0   = blockIdx.y * MB + wave * MT;   // swapped: m from y
    const int jt0  = blockIdx.x * JTILES;           // swapped: j from x (fast dim)

    const int col  = lane & 31;   // A row / B col / C col
    const int half = lane >> 5;   // k-half for A/B frags; row-group for C

    // A fragment, loaded once (K=16 == D)
    const short8 af = *(const short8*)(xe16 + (size_t)(m0 + col) * KDE_D + half * 8);

    // C operand = pe for the 16 C rows this lane owns: row = (r&3)+8*(r>>2)+4*half
    float16_t perv;
    #pragma unroll
    for (int r = 0; r < 16; ++r)
        perv[r] = pe[m0 + (r & 3) + 8 * (r >> 2) + 4 * half];

    const float INVN = 1.0f / (float)KDE_N;

    auto screen = [&](const float16_t& d, float thrv) {
        // max over this lane's 16 values, max3-friendly shape
        float m1 = fmaxf(fmaxf(d[0],  d[1]),  d[2]);
        float m2 = fmaxf(fmaxf(d[3],  d[4]),  d[5]);
        float m3 = fmaxf(fmaxf(d[6],  d[7]),  d[8]);
        float m4 = fmaxf(fmaxf(d[9],  d[10]), d[11]);
        float m5 = fmaxf(fmaxf(d[12], d[13]), d[14]);
        float x  = fmaxf(fmaxf(m1, m2), m3);
        float y  = fmaxf(fmaxf(m4, m5), d[15]);
        float mx = fmaxf(x, y);
        if (__any(mx > thrv)) {
            // rare: some term may exceed 2^-135
            const float pbv = THR - thrv;
            #pragma unroll
            for (int r = 0; r < 16; ++r) {
                float e = exp2f(d[r] + pbv);
                if (e != 0.f) {
                    const int row = m0 + (r & 3) + 8 * (r >> 2) + 4 * half;
                    float old  = atomicAdd(&S[row], e);
                    float cand = logf(1e-8f + (old + e) * INVN);
                    // all cands negative: float-max == uint-min on raw bits
                    atomicMin((unsigned int*)&out[row], __float_as_uint(cand));
                }
            }
        }
    };

    const unsigned short* bp = xb16 + (size_t)(jt0 * 32 + col) * KDE_D + half * 8;
    const float*          tp = pbthr + (jt0 * 32 + col);
    short8 bf   = *(const short8*)bp;
    float  thrv = *tp;

    #pragma unroll 4
    for (int t = 0; t < JTILES - 1; ++t) {
        bp += 32 * KDE_D;  tp += 32;
        const short8 bf_n  = *(const short8*)bp;
        const float  thr_n = *tp;
        float16_t d = __builtin_amdgcn_mfma_f32_32x32x16_bf16(af, bf, perv, 0, 0, 0);
        screen(d, thrv);
        bf = bf_n; thrv = thr_n;
    }
    {   // peeled last tile (no prefetch)
        float16_t d = __builtin_amdgcn_mfma_f32_32x32x16_bf16(af, bf, perv, 0, 0, 0);
        screen(d, thrv);
    }
}

extern "C" void kernel_launch(void* const* d_in, const int* in_sizes, int n_in,
                              void* d_out, int out_size, void* d_ws, size_t ws_size,
                              hipStream_t stream)
{
    const float* xe = (const float*)d_in[0];  // x_eval [16384,16] fp32
    const float* xb = (const float*)d_in[1];  // x_base [16384,16] fp32
    float* out = (float*)d_out;

    // ws layout: S[16384] | pe[16384] | pbthr[16384] | xe16 | xb16
    float* S     = (float*)d_ws;
    float* pe    = S + KDE_N;
    float* pbthr = pe + KDE_N;
    unsigned short* xe16 = (unsigned short*)(pbthr + KDE_N);
    unsigned short* xb16 = xe16 + (size_t)KDE_N * KDE_D;

    kde_pre<<<(2 * KDE_N) / 256, 256, 0, stream>>>(xe, xb, S, pe, pbthr, xe16, xb16, out);
    dim3 grid(JSPLIT, KDE_N / MB);   // (16, 128): j-slice in FAST dim ->
                                     // co-resident blocks share one 32 KB B-slice
    kde_main<<<grid, MWAVES * 64, 0, stream>>>(xe16, xb16, pe, pbthr, S, out);
}

// Round 4
// 66.582 us; speedup vs baseline: 1.0921x; 1.0268x over previous
//
#include <hip/hip_runtime.h>
#include <math.h>

// KDE log-density: out[i] = log(1e-8 + (1/N) * sum_j exp(t1 - 50*||xe_i - xb_j||^2))
// N = 16384, D = 16, fp32 in/out.
//
// Round 9: LDS-fed B operand. Round-8 post-mortem: kde_main (~7 us) is
// L1-BANDWIDTH bound, not locality bound: 32 waves/CU x 32 KB B-slice =
// 1 MB/CU through L1 at ~64 B/cyc = ~6.7 us == observed. Grid swizzle
// (round 8) made these hits but hit-BW is the wall; leaner loop bodies
// (rounds 6/7) never touched this term.
//  - Fix: 512-thread blocks (8 waves), grid(16,64) = 1024 blocks = exactly
//    4/CU at 8 waves/SIMD. Each block stages its 32 KB bf16 B-slice + 4 KB
//    thr slice into LDS once (contiguous 16B/lane: conflict-free, coalesced),
//    one barrier, then 32 tiles of ds_read_b128 (256 B/cyc LDS vs 64 B/cyc
//    L1) + MFMA + the VERBATIM round-5 screen. In-loop global traffic: zero.
//  - LDS 36 KB x 4 blocks = 144 KB <= 160. VGPR budget unchanged (<=64 at
//    8 waves/SIMD). kde_pre, conversion math, screen, rare path: untouched.

#define KDE_N 16384
#define KDE_D 16
#define MT 32                  // rows per wave m-tile
#define MWAVES 8               // waves per block
#define MB (MT * MWAVES)       // 256 eval rows per block
#define JSPLIT 16
#define JTILES (KDE_N / 32 / JSPLIT)   // 32 j-tiles per wave
#define THR (-135.0f)          // log2-domain underflow screen

typedef __attribute__((ext_vector_type(8)))  short   short8;
typedef __attribute__((ext_vector_type(16))) float   float16_t;

__device__ __forceinline__ unsigned short f32_to_bf16_rne(float f) {
    unsigned int u = __float_as_uint(f);
    unsigned int r = (u + 0x7FFFu + ((u >> 16) & 1u)) >> 16;
    return (unsigned short)r;
}

// ---- prologue: pe / (THR - pb), scaled bf16 casts, zero S, default out ----
__global__ void kde_pre(const float* __restrict__ xe, const float* __restrict__ xb,
                        float* __restrict__ S, float* __restrict__ pe,
                        float* __restrict__ pbthr, unsigned short* __restrict__ xe16,
                        unsigned short* __restrict__ xb16, float* __restrict__ out)
{
    const int t = blockIdx.x * blockDim.x + threadIdx.x;   // 0..32767
    const int row = t & (KDE_N - 1);
    const bool isB = t >= KDE_N;
    const float* src = (isB ? xb : xe) + (size_t)row * KDE_D;
    const float4* s4 = (const float4*)src;
    const float SQSC = 12.011224664550577f;   // sqrt(100*log2e)
    float q = 0.f;
    unsigned int w[8];
    #pragma unroll
    for (int k = 0; k < 4; ++k) {
        float4 v = s4[k];
        q += v.x*v.x + v.y*v.y + v.z*v.z + v.w*v.w;
        w[2*k+0] = (unsigned int)f32_to_bf16_rne(v.x * SQSC)
                 | ((unsigned int)f32_to_bf16_rne(v.y * SQSC) << 16);
        w[2*k+1] = (unsigned int)f32_to_bf16_rne(v.z * SQSC)
                 | ((unsigned int)f32_to_bf16_rne(v.w * SQSC) << 16);
    }
    unsigned short* dst = (isB ? xb16 : xe16) + (size_t)row * KDE_D;
    uint4* d4 = (uint4*)dst;
    d4[0] = make_uint4(w[0], w[1], w[2], w[3]);
    d4[1] = make_uint4(w[4], w[5], w[6], w[7]);
    const float T1L2E  = -17.8920067984f;       // log2e * t1
    const float C72    = 72.134752044447963f;   // 50 * log2e
    const float LOG1EM8 = -18.420680743952367f; // log(1e-8)
    if (!isB) { pe[row] = T1L2E - C72 * q; S[row] = 0.f; out[row] = LOG1EM8; }
    else      { pbthr[row] = THR + C72 * q; }   // THR - pb,  pb = -C72*b2
}

// ---- main: LDS-staged B + MFMA + max-screen; rare exp path as round 5 ----
__global__ __launch_bounds__(512, 8) void kde_main(
    const unsigned short* __restrict__ xe16, const unsigned short* __restrict__ xb16,
    const float* __restrict__ pe, const float* __restrict__ pbthr,
    float* __restrict__ S, float* __restrict__ out)
{
    // smem layout: B-slice bf16 [1024 rows x 32 B] = 32 KB | thr [1024 f32] = 4 KB
    __shared__ char smem[36864];

    const int tid  = threadIdx.x;
    const int lane = tid & 63;
    const int wave = tid >> 6;                      // 0..7
    const int m0   = blockIdx.y * MB + wave * MT;
    const int jt0  = blockIdx.x * JTILES;           // j-slice in fast dim

    // ---- stage B-slice (32 KB) + thr (4 KB) into LDS; fully coalesced,
    //      conflict-free (contiguous 16 B per lane per instruction) ----
    {
        const char* gsrc = (const char*)xb16 + (size_t)jt0 * 32 * KDE_D * sizeof(short);
        #pragma unroll
        for (int k = 0; k < 4; ++k) {
            const int off = k * 8192 + tid * 16;
            *(uint4*)(smem + off) = *(const uint4*)(gsrc + off);
        }
        if (tid < 256) {
            const int off = tid * 16;
            *(uint4*)(smem + 32768 + off) =
                *(const uint4*)((const char*)(pbthr + jt0 * 32) + off);
        }
    }

    const int col  = lane & 31;   // A row / B col / C col
    const int half = lane >> 5;   // k-half for A/B frags; row-group for C

    // A fragment, loaded once (K=16 == D)
    const short8 af = *(const short8*)(xe16 + (size_t)(m0 + col) * KDE_D + half * 8);

    // C operand = pe for the 16 C rows this lane owns: row = (r&3)+8*(r>>2)+4*half
    float16_t perv;
    #pragma unroll
    for (int r = 0; r < 16; ++r)
        perv[r] = pe[m0 + (r & 3) + 8 * (r >> 2) + 4 * half];

    const float INVN = 1.0f / (float)KDE_N;

    auto screen = [&](const float16_t& d, float thrv) {
        // max over this lane's 16 values, max3-friendly shape
        float m1 = fmaxf(fmaxf(d[0],  d[1]),  d[2]);
        float m2 = fmaxf(fmaxf(d[3],  d[4]),  d[5]);
        float m3 = fmaxf(fmaxf(d[6],  d[7]),  d[8]);
        float m4 = fmaxf(fmaxf(d[9],  d[10]), d[11]);
        float m5 = fmaxf(fmaxf(d[12], d[13]), d[14]);
        float x  = fmaxf(fmaxf(m1, m2), m3);
        float y  = fmaxf(fmaxf(m4, m5), d[15]);
        float mx = fmaxf(x, y);
        if (__any(mx > thrv)) {
            // rare: some term may exceed 2^-135
            const float pbv = THR - thrv;
            #pragma unroll
            for (int r = 0; r < 16; ++r) {
                float e = exp2f(d[r] + pbv);
                if (e != 0.f) {
                    const int row = m0 + (r & 3) + 8 * (r >> 2) + 4 * half;
                    float old  = atomicAdd(&S[row], e);
                    float cand = logf(1e-8f + (old + e) * INVN);
                    // all cands negative: float-max == uint-min on raw bits
                    atomicMin((unsigned int*)&out[row], __float_as_uint(cand));
                }
            }
        }
    };

    __syncthreads();   // B-slice + thr resident

    // per-lane LDS base: row 'col' of a tile, k-half 'half'
    const int lbase = col * 32 + half * 16;

    short8 bf   = *(const short8*)(smem + lbase);
    float  thrv = *(const float*)(smem + 32768 + col * 4);

    #pragma unroll 4
    for (int t = 0; t < JTILES - 1; ++t) {
        const short8 bf_n  = *(const short8*)(smem + (t + 1) * 1024 + lbase);
        const float  thr_n = *(const float*)(smem + 32768 + (t + 1) * 128 + col * 4);
        float16_t d = __builtin_amdgcn_mfma_f32_32x32x16_bf16(af, bf, perv, 0, 0, 0);
        screen(d, thrv);
        bf = bf_n; thrv = thr_n;
    }
    {   // peeled last tile (no prefetch)
        float16_t d = __builtin_amdgcn_mfma_f32_32x32x16_bf16(af, bf, perv, 0, 0, 0);
        screen(d, thrv);
    }
}

extern "C" void kernel_launch(void* const* d_in, const int* in_sizes, int n_in,
                              void* d_out, int out_size, void* d_ws, size_t ws_size,
                              hipStream_t stream)
{
    const float* xe = (const float*)d_in[0];  // x_eval [16384,16] fp32
    const float* xb = (const float*)d_in[1];  // x_base [16384,16] fp32
    float* out = (float*)d_out;

    // ws layout: S[16384] | pe[16384] | pbthr[16384] | xe16 | xb16
    float* S     = (float*)d_ws;
    float* pe    = S + KDE_N;
    float* pbthr = pe + KDE_N;
    unsigned short* xe16 = (unsigned short*)(pbthr + KDE_N);
    unsigned short* xb16 = xe16 + (size_t)KDE_N * KDE_D;

    kde_pre<<<(2 * KDE_N) / 256, 256, 0, stream>>>(xe, xb, S, pe, pbthr, xe16, xb16, out);
    dim3 grid(JSPLIT, KDE_N / MB);   // (16, 64) = 1024 blocks = 4/CU, fully resident
    kde_main<<<grid, MWAVES * 64, 0, stream>>>(xe16, xb16, pe, pbthr, S, out);
}